// Round 3
// baseline (357.161 us; speedup 1.0000x reference)
//
#include <hip/hip_runtime.h>
#include <cstdint>

typedef __bf16 bf16x8 __attribute__((ext_vector_type(8)));
typedef float  f32x4  __attribute__((ext_vector_type(4)));

__device__ __forceinline__ unsigned short f2bf(float f) {
    unsigned int x; __builtin_memcpy(&x, &f, 4);
    unsigned int r = x + 0x7fffu + ((x >> 16) & 1u);
    return (unsigned short)(r >> 16);
}
// split 8 f32 into hi/lo bf16 fragments (hi+lo ~ 16-bit mantissa)
__device__ __forceinline__ void split8(const float* v, bf16x8& hi, bf16x8& lo) {
    union { bf16x8 v; __bf16 e[8]; } h, l;
    #pragma unroll
    for (int j = 0; j < 8; j++) {
        __bf16 hb = (__bf16)v[j];
        float  r  = v[j] - (float)hb;
        h.e[j] = hb; l.e[j] = (__bf16)r;
    }
    hi = h.v; lo = l.v;
}
__device__ __forceinline__ void splitstore(unsigned short* ph, unsigned short* pl, float v) {
    __bf16 hb = (__bf16)v;
    float  r  = v - (float)hb;
    __bf16 lb = (__bf16)r;
    unsigned short hu, lu;
    __builtin_memcpy(&hu, &hb, 2); __builtin_memcpy(&lu, &lb, 2);
    *ph = hu; *pl = lu;
}

// ---------------- K0: w~ = W1[t]^T @ a  (f1 rows 0..3, f2 rows 4..7) ----------
__global__ __launch_bounds__(64)
void k0_wtilde(const float* __restrict__ w1,
               const float* __restrict__ a11,
               const float* __restrict__ a21,
               float* __restrict__ wt) {
    int wg = blockIdx.x;
    int t = wg & 3, which = wg >> 2;
    const float* a = which ? a21 : a11;
    int lane = threadIdx.x;
    float acc0 = 0.f, acc1 = 0.f, acc2 = 0.f, acc3 = 0.f;
    for (int d = 0; d < 64; d++) {
        float av = a[t * 64 + d];
        const float* wr = w1 + (t * 64 + d) * 256 + lane * 4;
        acc0 += av * wr[0]; acc1 += av * wr[1];
        acc2 += av * wr[2]; acc3 += av * wr[3];
    }
    float* o = wt + (which * 4 + t) * 256 + lane * 4;
    o[0] = acc0; o[1] = acc1; o[2] = acc2; o[3] = acc3;
}

// ---------------- Kpre: adjacency bitmask via ballot --------------------------
__global__ __launch_bounds__(256)
void kpre_bitmask(const int* __restrict__ adj, unsigned long long* __restrict__ bm) {
    int row = blockIdx.x;
    int wave = threadIdx.x >> 6, lane = threadIdx.x & 63;
    #pragma unroll
    for (int it = 0; it < 16; it++) {
        int jb = it * 256 + wave * 64;
        int v = adj[row * 4096 + jb + lane];
        unsigned long long mask = __ballot(v != 0);
        if (lane == 0) bm[row * 64 + (jb >> 6)] = mask;
    }
}

// ---------------- K1: H1T[c][i] = (x @ W1^T)[i][c], hi/lo bf16 out ------------
__global__ __launch_bounds__(256)
void k1_gemm(const float* __restrict__ x,
             const float* __restrict__ w1,
             unsigned short* __restrict__ h1t_hi,
             unsigned short* __restrict__ h1t_lo) {
    int tid = threadIdx.x, wave = tid >> 6, lane = tid & 63;
    int q = lane >> 4, m = lane & 15;
    int i0 = blockIdx.x * 16;
    int c0 = wave * 64;
    f32x4 acc[4] = {};
    #pragma unroll
    for (int k0 = 0; k0 < 256; k0 += 32) {
        bf16x8 ah, al;
        split8(x + (i0 + m) * 256 + k0 + q * 8, ah, al);
        #pragma unroll
        for (int ct = 0; ct < 4; ct++) {
            bf16x8 bh, bl;
            split8(w1 + (c0 + ct * 16 + m) * 256 + k0 + q * 8, bh, bl);
            acc[ct] = __builtin_amdgcn_mfma_f32_16x16x32_bf16(ah, bh, acc[ct], 0, 0, 0);
            acc[ct] = __builtin_amdgcn_mfma_f32_16x16x32_bf16(al, bh, acc[ct], 0, 0, 0);
            acc[ct] = __builtin_amdgcn_mfma_f32_16x16x32_bf16(ah, bl, acc[ct], 0, 0, 0);
        }
    }
    #pragma unroll
    for (int ct = 0; ct < 4; ct++)
        #pragma unroll
        for (int r = 0; r < 4; r++) {
            int c = c0 + ct * 16 + m, i = i0 + q * 4 + r;
            splitstore(&h1t_hi[c * 4096 + i], &h1t_lo[c * 4096 + i], acc[ct][r]);
        }
}

// ---------------- K1c: f1/f2 = x @ w~  ([8][4096] f32, exact) -----------------
__global__ __launch_bounds__(256)
void k1c_fvals(const float* __restrict__ x,
               const float* __restrict__ wt,
               float* __restrict__ fout) {
    int tid = threadIdx.x, wave = tid >> 6, lane = tid & 63;
    int i = blockIdx.x * 4 + wave;
    const float4 xv = *(const float4*)(x + i * 256 + lane * 4);
    #pragma unroll
    for (int a = 0; a < 8; a++) {
        const float4 wv = *(const float4*)(wt + a * 256 + lane * 4);
        float s = xv.x * wv.x + xv.y * wv.y + xv.z * wv.z + xv.w * wv.w;
        #pragma unroll
        for (int off = 32; off >= 1; off >>= 1) s += __shfl_xor(s, off);
        if (lane == 0) fout[a * 4096 + i] = s;
    }
}

// ---------------- attention: out = softmax(mask(lrelu(f1_i+f2_j))) @ H --------
// no-max-subtraction softmax (e bounded: max|e|~6, exp<400), single pass.
// PV in hi/lo bf16 (3 MFMAs) -> ~f32 accuracy. Z from exact f32 p via shuffle.
// wg = 256 thr = 4 waves: (rowgroup rg in {0,1} of 32-row tile) x (j-half).
template<int NCT, bool LAYER1>
__global__ __launch_bounds__(256)
void attn_kernel(const unsigned char* __restrict__ bmb,
                 const float* __restrict__ f1_all,
                 const float* __restrict__ f2_all,
                 const unsigned short* __restrict__ BTh_all,
                 const unsigned short* __restrict__ BTl_all,
                 unsigned short* __restrict__ outh,
                 unsigned short* __restrict__ outl,
                 float* __restrict__ outf,
                 int ostride) {
    int tid = threadIdx.x, wave = tid >> 6, lane = tid & 63;
    int rg = wave >> 1, jh = wave & 1;
    int q = lane >> 4, m = lane & 15;
    int head = blockIdx.y;
    int i0 = blockIdx.x * 32;
    int row = i0 + rg * 16 + m;

    const float* f1 = f1_all + head * 4096;
    const float* f2 = f2_all + head * 4096;
    const unsigned short* BTh = BTh_all + head * NCT * 16 * 4096;
    const unsigned short* BTl = BTl_all + head * NCT * 16 * 4096;
    int col0 = head * NCT * 16;

    float f1s = f1[row];
    f32x4 acc[NCT] = {};
    float z = 0.f;

    int jstart = jh * 2048;
    for (int j0 = jstart; j0 < jstart + 2048; j0 += 32) {
        unsigned int mb = bmb[row * 512 + (j0 >> 3) + q];
        const float4* f2p = (const float4*)(f2 + j0 + q * 8);
        float4 fa = f2p[0], fb = f2p[1];
        float fv[8] = {fa.x, fa.y, fa.z, fa.w, fb.x, fb.y, fb.z, fb.w};
        float pv[8];
        #pragma unroll
        for (int jj = 0; jj < 8; jj++) {
            float s = f1s + fv[jj];
            float e = fmaxf(s, 0.01f * s);           // leaky_relu
            bool valid = ((mb >> jj) & 1u) && (s != 0.0f);
            float p = valid ? __expf(e) : 0.0f;
            z += p;
            pv[jj] = p;
        }
        bf16x8 ah, al;
        split8(pv, ah, al);
        #pragma unroll
        for (int ct = 0; ct < NCT; ct++) {
            bf16x8 bh = *(const bf16x8*)(BTh + (ct * 16 + m) * 4096 + j0 + q * 8);
            bf16x8 bl = *(const bf16x8*)(BTl + (ct * 16 + m) * 4096 + j0 + q * 8);
            acc[ct] = __builtin_amdgcn_mfma_f32_16x16x32_bf16(ah, bh, acc[ct], 0, 0, 0);
            acc[ct] = __builtin_amdgcn_mfma_f32_16x16x32_bf16(al, bh, acc[ct], 0, 0, 0);
            acc[ct] = __builtin_amdgcn_mfma_f32_16x16x32_bf16(ah, bl, acc[ct], 0, 0, 0);
        }
    }
    // z: partial for row m over this lane's k-chunk; reduce over quads
    z += __shfl_xor(z, 16);
    z += __shfl_xor(z, 32);

    __shared__ float accbuf[2][16][NCT * 16];
    __shared__ float zbuf[2][16];
    __shared__ float zbuf2[2][16];

    if (jh == 1) {
        #pragma unroll
        for (int ct = 0; ct < NCT; ct++)
            #pragma unroll
            for (int r = 0; r < 4; r++)
                accbuf[rg][q * 4 + r][ct * 16 + m] = acc[ct][r];
        if (lane < 16) zbuf[rg][lane] = z;
    }
    __syncthreads();
    if (jh == 0) {
        #pragma unroll
        for (int ct = 0; ct < NCT; ct++)
            #pragma unroll
            for (int r = 0; r < 4; r++)
                acc[ct][r] += accbuf[rg][q * 4 + r][ct * 16 + m];
        z += zbuf[rg][m];
        if (lane < 16) zbuf2[rg][lane] = z;
    }
    __syncthreads();
    if (jh == 0) {
        float rz[4];
        #pragma unroll
        for (int r = 0; r < 4; r++) rz[r] = 1.0f / zbuf2[rg][q * 4 + r];
        #pragma unroll
        for (int ct = 0; ct < NCT; ct++)
            #pragma unroll
            for (int r = 0; r < 4; r++) {
                float v = acc[ct][r] * rz[r];
                int orow = i0 + rg * 16 + q * 4 + r;
                int oc = orow * ostride + col0 + ct * 16 + m;
                if (LAYER1) {
                    v = (v > 0.f) ? v : (__expf(v) - 1.0f);   // elu
                    splitstore(&outh[oc], &outl[oc], v);
                } else {
                    outf[oc] = v;
                }
            }
    }
}

// ---------------- K3: h2 = h_elu @ W2^T (hi/lo), f1_2/f2_2, h2T hi/lo ---------
__global__ __launch_bounds__(256)
void k3_layer2(const unsigned short* __restrict__ helu_hi,
               const unsigned short* __restrict__ helu_lo,
               const float* __restrict__ w2,
               const float* __restrict__ a12,
               const float* __restrict__ a22,
               unsigned short* __restrict__ h2t_hi,
               unsigned short* __restrict__ h2t_lo,
               float* __restrict__ fq) {
    int tid = threadIdx.x, wave = tid >> 6, lane = tid & 63;
    int q = lane >> 4, m = lane & 15;
    int i0 = (blockIdx.x * 4 + wave) * 16;
    f32x4 acc = {};
    #pragma unroll
    for (int k0 = 0; k0 < 256; k0 += 32) {
        bf16x8 ah = *(const bf16x8*)(helu_hi + (i0 + m) * 256 + k0 + q * 8);
        bf16x8 al = *(const bf16x8*)(helu_lo + (i0 + m) * 256 + k0 + q * 8);
        bf16x8 bh, bl;
        split8(w2 + m * 256 + k0 + q * 8, bh, bl);
        acc = __builtin_amdgcn_mfma_f32_16x16x32_bf16(ah, bh, acc, 0, 0, 0);
        acc = __builtin_amdgcn_mfma_f32_16x16x32_bf16(al, bh, acc, 0, 0, 0);
        acc = __builtin_amdgcn_mfma_f32_16x16x32_bf16(ah, bl, acc, 0, 0, 0);
    }
    float a1v = a12[m], a2v = a22[m];
    #pragma unroll
    for (int r = 0; r < 4; r++) {
        float v = acc[r];
        int i = i0 + q * 4 + r;
        splitstore(&h2t_hi[m * 4096 + i], &h2t_lo[m * 4096 + i], v);
        float s1 = v * a1v, s2 = v * a2v;
        #pragma unroll
        for (int off = 1; off < 16; off <<= 1) {
            s1 += __shfl_xor(s1, off);
            s2 += __shfl_xor(s2, off);
        }
        if (m == 0) { fq[i] = s1; fq[4096 + i] = s2; }
    }
}

extern "C" void kernel_launch(void* const* d_in, const int* in_sizes, int n_in,
                              void* d_out, int out_size, void* d_ws, size_t ws_size,
                              hipStream_t stream) {
    const float* x   = (const float*)d_in[0];
    const int*   adj = (const int*)d_in[1];
    const float* w1  = (const float*)d_in[2];
    const float* a11 = (const float*)d_in[3];
    const float* a21 = (const float*)d_in[4];
    const float* w2  = (const float*)d_in[5];
    const float* a12 = (const float*)d_in[6];
    const float* a22 = (const float*)d_in[7];
    float* out = (float*)d_out;

    uint8_t* w = (uint8_t*)d_ws;
    unsigned long long* bm    = (unsigned long long*)(w);                     // 2 MB
    unsigned short* h1t_hi  = (unsigned short*)(w + (2u  << 20));             // 2 MB
    unsigned short* h1t_lo  = (unsigned short*)(w + (4u  << 20));             // 2 MB
    unsigned short* helu_hi = (unsigned short*)(w + (6u  << 20));             // 2 MB
    unsigned short* helu_lo = (unsigned short*)(w + (8u  << 20));             // 2 MB
    unsigned short* h2t_hi  = (unsigned short*)(w + (10u << 20));             // 128 KB
    unsigned short* h2t_lo  = (unsigned short*)(w + (10u << 20) + (128u << 10)); // 128 KB
    float*          wt      = (float*)(w + (10u << 20) + (256u << 10));       // 8 KB
    float*          fvals   = (float*)(w + (10u << 20) + (288u << 10));       // 128 KB
    float*          fq      = (float*)(w + (10u << 20) + (416u << 10));       // 32 KB

    k0_wtilde<<<8, 64, 0, stream>>>(w1, a11, a21, wt);
    kpre_bitmask<<<4096, 256, 0, stream>>>(adj, bm);
    k1_gemm<<<256, 256, 0, stream>>>(x, w1, h1t_hi, h1t_lo);
    k1c_fvals<<<1024, 256, 0, stream>>>(x, wt, fvals);
    attn_kernel<4, true><<<dim3(128, 4), 256, 0, stream>>>(
        (const unsigned char*)bm, fvals, fvals + 4 * 4096, h1t_hi, h1t_lo,
        helu_hi, helu_lo, nullptr, 256);
    k3_layer2<<<64, 256, 0, stream>>>(helu_hi, helu_lo, w2, a12, a22,
                                      h2t_hi, h2t_lo, fq);
    attn_kernel<1, false><<<dim3(128, 1), 256, 0, stream>>>(
        (const unsigned char*)bm, fq, fq + 4096, h2t_hi, h2t_lo,
        nullptr, nullptr, out, 16);
}

// Round 4
// 315.936 us; speedup vs baseline: 1.1305x; 1.1305x over previous
//
#include <hip/hip_runtime.h>
#include <cstdint>

typedef __bf16 bf16x8 __attribute__((ext_vector_type(8)));
typedef float  f32x4  __attribute__((ext_vector_type(4)));

// split 8 f32 into hi/lo bf16 fragments (hi+lo ~ 16-bit mantissa)
__device__ __forceinline__ void split8(const float* v, bf16x8& hi, bf16x8& lo) {
    union { bf16x8 v; __bf16 e[8]; } h, l;
    #pragma unroll
    for (int j = 0; j < 8; j++) {
        __bf16 hb = (__bf16)v[j];
        float  r  = v[j] - (float)hb;
        h.e[j] = hb; l.e[j] = (__bf16)r;
    }
    hi = h.v; lo = l.v;
}
__device__ __forceinline__ void splitstore(unsigned short* ph, unsigned short* pl, float v) {
    __bf16 hb = (__bf16)v;
    float  r  = v - (float)hb;
    __bf16 lb = (__bf16)r;
    unsigned short hu, lu;
    __builtin_memcpy(&hu, &hb, 2); __builtin_memcpy(&lu, &lb, 2);
    *ph = hu; *pl = lu;
}

// ---------------- Kzero: zero the atomic-accumulation region ------------------
__global__ __launch_bounds__(256)
void kzero(float4* __restrict__ p) {
    p[blockIdx.x * 256 + threadIdx.x] = float4{0.f, 0.f, 0.f, 0.f};
}

// ---------------- Ksplit: presplit W1/W2 into hi/lo bf16 ----------------------
__global__ __launch_bounds__(256)
void ksplit(const float* __restrict__ w1, const float* __restrict__ w2,
            unsigned short* __restrict__ w1h, unsigned short* __restrict__ w1l,
            unsigned short* __restrict__ w2h, unsigned short* __restrict__ w2l) {
    int e = (blockIdx.x * 256 + threadIdx.x) * 4;
    const float* src; unsigned short *dh, *dl;
    if (e < 65536) { src = w1 + e; dh = w1h + e; dl = w1l + e; }
    else { int e2 = e - 65536; src = w2 + e2; dh = w2h + e2; dl = w2l + e2; }
    #pragma unroll
    for (int j = 0; j < 4; j++) splitstore(dh + j, dl + j, src[j]);
}

// ---------------- K0: w~ = W1[t]^T @ a  (f1 rows 0..3, f2 rows 4..7) ----------
__global__ __launch_bounds__(64)
void k0_wtilde(const float* __restrict__ w1,
               const float* __restrict__ a11,
               const float* __restrict__ a21,
               float* __restrict__ wt) {
    int wg = blockIdx.x;
    int t = wg & 3, which = wg >> 2;
    const float* a = which ? a21 : a11;
    int lane = threadIdx.x;
    float acc0 = 0.f, acc1 = 0.f, acc2 = 0.f, acc3 = 0.f;
    for (int d = 0; d < 64; d++) {
        float av = a[t * 64 + d];
        const float* wr = w1 + (t * 64 + d) * 256 + lane * 4;
        acc0 += av * wr[0]; acc1 += av * wr[1];
        acc2 += av * wr[2]; acc3 += av * wr[3];
    }
    float* o = wt + (which * 4 + t) * 256 + lane * 4;
    o[0] = acc0; o[1] = acc1; o[2] = acc2; o[3] = acc3;
}

// ---------------- Kpre: adjacency bitmask via ballot --------------------------
__global__ __launch_bounds__(256)
void kpre_bitmask(const int* __restrict__ adj, unsigned long long* __restrict__ bm) {
    int row = blockIdx.x;
    int wave = threadIdx.x >> 6, lane = threadIdx.x & 63;
    #pragma unroll
    for (int it = 0; it < 16; it++) {
        int jb = it * 256 + wave * 64;
        int v = adj[row * 4096 + jb + lane];
        unsigned long long mask = __ballot(v != 0);
        if (lane == 0) bm[row * 64 + (jb >> 6)] = mask;
    }
}

// ---------------- K1: H1T[c][i] = (x @ W1^T)[i][c], hi/lo bf16 out ------------
__global__ __launch_bounds__(256)
void k1_gemm(const float* __restrict__ x,
             const unsigned short* __restrict__ w1h,
             const unsigned short* __restrict__ w1l,
             unsigned short* __restrict__ h1t_hi,
             unsigned short* __restrict__ h1t_lo) {
    int tid = threadIdx.x, wave = tid >> 6, lane = tid & 63;
    int q = lane >> 4, m = lane & 15;
    int i0 = blockIdx.x * 16;
    int c0 = wave * 64;
    f32x4 acc[4] = {};
    #pragma unroll
    for (int k0 = 0; k0 < 256; k0 += 32) {
        bf16x8 ah, al;
        split8(x + (i0 + m) * 256 + k0 + q * 8, ah, al);
        #pragma unroll
        for (int ct = 0; ct < 4; ct++) {
            bf16x8 bh = *(const bf16x8*)(w1h + (c0 + ct * 16 + m) * 256 + k0 + q * 8);
            bf16x8 bl = *(const bf16x8*)(w1l + (c0 + ct * 16 + m) * 256 + k0 + q * 8);
            acc[ct] = __builtin_amdgcn_mfma_f32_16x16x32_bf16(ah, bh, acc[ct], 0, 0, 0);
            acc[ct] = __builtin_amdgcn_mfma_f32_16x16x32_bf16(al, bh, acc[ct], 0, 0, 0);
            acc[ct] = __builtin_amdgcn_mfma_f32_16x16x32_bf16(ah, bl, acc[ct], 0, 0, 0);
        }
    }
    #pragma unroll
    for (int ct = 0; ct < 4; ct++)
        #pragma unroll
        for (int r = 0; r < 4; r++) {
            int c = c0 + ct * 16 + m, i = i0 + q * 4 + r;
            splitstore(&h1t_hi[c * 4096 + i], &h1t_lo[c * 4096 + i], acc[ct][r]);
        }
}

// ---------------- K1c: f1/f2 = x @ w~  ([8][4096] f32, exact) -----------------
__global__ __launch_bounds__(256)
void k1c_fvals(const float* __restrict__ x,
               const float* __restrict__ wt,
               float* __restrict__ fout) {
    int tid = threadIdx.x, wave = tid >> 6, lane = tid & 63;
    int i = blockIdx.x * 4 + wave;
    const float4 xv = *(const float4*)(x + i * 256 + lane * 4);
    #pragma unroll
    for (int a = 0; a < 8; a++) {
        const float4 wv = *(const float4*)(wt + a * 256 + lane * 4);
        float s = xv.x * wv.x + xv.y * wv.y + xv.z * wv.z + xv.w * wv.w;
        #pragma unroll
        for (int off = 32; off >= 1; off >>= 1) s += __shfl_xor(s, off);
        if (lane == 0) fout[a * 4096 + i] = s;
    }
}

// ---------------- attention (j-split, atomic partial accumulation) ------------
// no-max-subtraction softmax (e bounded), PV in hi/lo bf16 (3 MFMAs).
// grid (128 i-tiles, heads, 8 j-chunks); 4 waves = 2 rowgroups x 2 j-halves.
// Each wave atomically adds its partial acc (C-layout) and z into global.
template<int NCT>
__global__ __launch_bounds__(256)
void attn_kernel(const unsigned char* __restrict__ bmb,
                 const float* __restrict__ f1_all,
                 const float* __restrict__ f2_all,
                 const unsigned short* __restrict__ BTh_all,
                 const unsigned short* __restrict__ BTl_all,
                 float* __restrict__ pacc,
                 float* __restrict__ zacc,
                 int pstride) {
    int tid = threadIdx.x, wave = tid >> 6, lane = tid & 63;
    int rg = wave >> 1, jh = wave & 1;
    int q = lane >> 4, m = lane & 15;
    int head = blockIdx.y;
    int i0 = blockIdx.x * 32;
    int row = i0 + rg * 16 + m;

    const float* f1 = f1_all + head * 4096;
    const float* f2 = f2_all + head * 4096;
    const unsigned short* BTh = BTh_all + head * NCT * 16 * 4096;
    const unsigned short* BTl = BTl_all + head * NCT * 16 * 4096;
    int col0 = head * NCT * 16;

    float f1s = f1[row];
    f32x4 acc[NCT] = {};
    float z = 0.f;

    int jstart = blockIdx.z * 512 + jh * 256;
    #pragma unroll 2
    for (int j0 = jstart; j0 < jstart + 256; j0 += 32) {
        unsigned int mb = bmb[row * 512 + (j0 >> 3) + q];
        const float4* f2p = (const float4*)(f2 + j0 + q * 8);
        float4 fa = f2p[0], fb = f2p[1];
        float fv[8] = {fa.x, fa.y, fa.z, fa.w, fb.x, fb.y, fb.z, fb.w};
        float pv[8];
        #pragma unroll
        for (int jj = 0; jj < 8; jj++) {
            float s = f1s + fv[jj];
            float e = fmaxf(s, 0.01f * s);           // leaky_relu
            bool valid = ((mb >> jj) & 1u) && (s != 0.0f);
            float p = valid ? __expf(e) : 0.0f;
            z += p;
            pv[jj] = p;
        }
        bf16x8 ah, al;
        split8(pv, ah, al);
        #pragma unroll
        for (int ct = 0; ct < NCT; ct++) {
            bf16x8 bh = *(const bf16x8*)(BTh + (ct * 16 + m) * 4096 + j0 + q * 8);
            bf16x8 bl = *(const bf16x8*)(BTl + (ct * 16 + m) * 4096 + j0 + q * 8);
            acc[ct] = __builtin_amdgcn_mfma_f32_16x16x32_bf16(ah, bh, acc[ct], 0, 0, 0);
            acc[ct] = __builtin_amdgcn_mfma_f32_16x16x32_bf16(al, bh, acc[ct], 0, 0, 0);
            acc[ct] = __builtin_amdgcn_mfma_f32_16x16x32_bf16(ah, bl, acc[ct], 0, 0, 0);
        }
    }
    // z: partial for row m over this lane's k-chunk; reduce over quads
    z += __shfl_xor(z, 16);
    z += __shfl_xor(z, 32);
    if (lane < 16) atomicAdd(&zacc[head * 4096 + i0 + rg * 16 + lane], z);
    #pragma unroll
    for (int ct = 0; ct < NCT; ct++)
        #pragma unroll
        for (int r = 0; r < 4; r++) {
            int orow = i0 + rg * 16 + q * 4 + r;
            atomicAdd(&pacc[orow * pstride + col0 + ct * 16 + m], acc[ct][r]);
        }
}

// ---------------- Fin1: helu = elu(p1/z1), hi/lo bf16 -------------------------
__global__ __launch_bounds__(256)
void fin1(const float* __restrict__ pacc, const float* __restrict__ zacc,
          unsigned short* __restrict__ hh, unsigned short* __restrict__ hl) {
    int t = threadIdx.x;
    int row = blockIdx.x * 16 + (t >> 4);
    int c0 = (t & 15) * 16;
    int head = c0 >> 6;
    float rz = 1.0f / zacc[head * 4096 + row];
    #pragma unroll
    for (int c = c0; c < c0 + 16; c++) {
        float v = pacc[row * 256 + c] * rz;
        v = (v > 0.f) ? v : (__expf(v) - 1.0f);
        splitstore(&hh[row * 256 + c], &hl[row * 256 + c], v);
    }
}

// ---------------- Fin2: out = p2/z2 (f32) -------------------------------------
__global__ __launch_bounds__(256)
void fin2(const float* __restrict__ pacc, const float* __restrict__ zacc,
          float* __restrict__ out) {
    int idx = blockIdx.x * 256 + threadIdx.x;      // 65536
    out[idx] = pacc[idx] / zacc[idx >> 4];
}

// ---------------- K3: h2 = h_elu @ W2^T (hi/lo), f1_2/f2_2, h2T hi/lo ---------
__global__ __launch_bounds__(256)
void k3_layer2(const unsigned short* __restrict__ helu_hi,
               const unsigned short* __restrict__ helu_lo,
               const unsigned short* __restrict__ w2h,
               const unsigned short* __restrict__ w2l,
               const float* __restrict__ a12,
               const float* __restrict__ a22,
               unsigned short* __restrict__ h2t_hi,
               unsigned short* __restrict__ h2t_lo,
               float* __restrict__ fq) {
    int tid = threadIdx.x, wave = tid >> 6, lane = tid & 63;
    int q = lane >> 4, m = lane & 15;
    int i0 = (blockIdx.x * 4 + wave) * 16;
    f32x4 acc = {};
    #pragma unroll
    for (int k0 = 0; k0 < 256; k0 += 32) {
        bf16x8 ah = *(const bf16x8*)(helu_hi + (i0 + m) * 256 + k0 + q * 8);
        bf16x8 al = *(const bf16x8*)(helu_lo + (i0 + m) * 256 + k0 + q * 8);
        bf16x8 bh = *(const bf16x8*)(w2h + m * 256 + k0 + q * 8);
        bf16x8 bl = *(const bf16x8*)(w2l + m * 256 + k0 + q * 8);
        acc = __builtin_amdgcn_mfma_f32_16x16x32_bf16(ah, bh, acc, 0, 0, 0);
        acc = __builtin_amdgcn_mfma_f32_16x16x32_bf16(al, bh, acc, 0, 0, 0);
        acc = __builtin_amdgcn_mfma_f32_16x16x32_bf16(ah, bl, acc, 0, 0, 0);
    }
    float a1v = a12[m], a2v = a22[m];
    #pragma unroll
    for (int r = 0; r < 4; r++) {
        float v = acc[r];
        int i = i0 + q * 4 + r;
        splitstore(&h2t_hi[m * 4096 + i], &h2t_lo[m * 4096 + i], v);
        float s1 = v * a1v, s2 = v * a2v;
        #pragma unroll
        for (int off = 1; off < 16; off <<= 1) {
            s1 += __shfl_xor(s1, off);
            s2 += __shfl_xor(s2, off);
        }
        if (m == 0) { fq[i] = s1; fq[4096 + i] = s2; }
    }
}

extern "C" void kernel_launch(void* const* d_in, const int* in_sizes, int n_in,
                              void* d_out, int out_size, void* d_ws, size_t ws_size,
                              hipStream_t stream) {
    const float* x   = (const float*)d_in[0];
    const int*   adj = (const int*)d_in[1];
    const float* w1  = (const float*)d_in[2];
    const float* a11 = (const float*)d_in[3];
    const float* a21 = (const float*)d_in[4];
    const float* w2  = (const float*)d_in[5];
    const float* a12 = (const float*)d_in[6];
    const float* a22 = (const float*)d_in[7];
    float* out = (float*)d_out;

    uint8_t* w = (uint8_t*)d_ws;
    unsigned long long* bm  = (unsigned long long*)(w);                       // 2 MB
    unsigned short* h1t_hi  = (unsigned short*)(w + (2u  << 20));             // 2 MB
    unsigned short* h1t_lo  = (unsigned short*)(w + (4u  << 20));             // 2 MB
    unsigned short* helu_hi = (unsigned short*)(w + (6u  << 20));             // 2 MB
    unsigned short* helu_lo = (unsigned short*)(w + (8u  << 20));             // 2 MB
    unsigned short* h2t_hi  = (unsigned short*)(w + (10u << 20));             // 128 KB
    unsigned short* h2t_lo  = (unsigned short*)(w + (10u << 20) + (128u << 10)); // 128 KB
    float*          wt      = (float*)(w + (10u << 20) + (256u << 10));       // 8 KB
    float*          fvals   = (float*)(w + (10u << 20) + (288u << 10));       // 128 KB
    float*          fq      = (float*)(w + (10u << 20) + (416u << 10));       // 32 KB
    unsigned short* w1h     = (unsigned short*)(w + (10u << 20) + (448u << 10)); // 128 KB
    unsigned short* w1l     = (unsigned short*)(w + (10u << 20) + (576u << 10)); // 128 KB
    unsigned short* w2h     = (unsigned short*)(w + (10u << 20) + (704u << 10)); // 8 KB
    unsigned short* w2l     = (unsigned short*)(w + (10u << 20) + (712u << 10)); // 8 KB
    float*          p1      = (float*)(w + (10u << 20) + (720u << 10));       // 4 MB
    float*          z1      = p1 + 4096 * 256;                                // 64 KB
    float*          p2      = z1 + 4 * 4096;                                  // 256 KB
    float*          z2      = p2 + 4096 * 16;                                 // 16 KB
    // zero region = p1..z2 = 1,134,592 floats = 283,648 float4 = 1108 blocks

    kzero<<<1108, 256, 0, stream>>>((float4*)p1);
    ksplit<<<68, 256, 0, stream>>>(w1, w2, w1h, w1l, w2h, w2l);
    k0_wtilde<<<8, 64, 0, stream>>>(w1, a11, a21, wt);
    kpre_bitmask<<<4096, 256, 0, stream>>>(adj, bm);
    k1_gemm<<<256, 256, 0, stream>>>(x, w1h, w1l, h1t_hi, h1t_lo);
    k1c_fvals<<<1024, 256, 0, stream>>>(x, wt, fvals);
    attn_kernel<4><<<dim3(128, 4, 8), 256, 0, stream>>>(
        (const unsigned char*)bm, fvals, fvals + 4 * 4096, h1t_hi, h1t_lo, p1, z1, 256);
    fin1<<<256, 256, 0, stream>>>(p1, z1, helu_hi, helu_lo);
    k3_layer2<<<64, 256, 0, stream>>>(helu_hi, helu_lo, w2h, w2l, a12, a22,
                                      h2t_hi, h2t_lo, fq);
    attn_kernel<1><<<dim3(128, 1, 8), 256, 0, stream>>>(
        (const unsigned char*)bm, fq, fq + 4096, h2t_hi, h2t_lo, p2, z2, 16);
    fin2<<<256, 256, 0, stream>>>(p2, z2, out);
}

// Round 5
// 243.030 us; speedup vs baseline: 1.4696x; 1.3000x over previous
//
#include <hip/hip_runtime.h>
#include <cstdint>

typedef __bf16 bf16x8 __attribute__((ext_vector_type(8)));
typedef float  f32x4  __attribute__((ext_vector_type(4)));

// split 8 f32 into hi/lo bf16 fragments (hi+lo ~ 16-bit mantissa)
__device__ __forceinline__ void split8(const float* v, bf16x8& hi, bf16x8& lo) {
    union { bf16x8 v; __bf16 e[8]; } h, l;
    #pragma unroll
    for (int j = 0; j < 8; j++) {
        __bf16 hb = (__bf16)v[j];
        float  r  = v[j] - (float)hb;
        h.e[j] = hb; l.e[j] = (__bf16)r;
    }
    hi = h.v; lo = l.v;
}
__device__ __forceinline__ void splitstore(unsigned short* ph, unsigned short* pl, float v) {
    __bf16 hb = (__bf16)v;
    float  r  = v - (float)hb;
    __bf16 lb = (__bf16)r;
    unsigned short hu, lu;
    __builtin_memcpy(&hu, &hb, 2); __builtin_memcpy(&lu, &lb, 2);
    *ph = hu; *pl = lu;
}
__device__ __forceinline__ unsigned short f2bfh(float v) {
    __bf16 hb = (__bf16)v; unsigned short hu;
    __builtin_memcpy(&hu, &hb, 2); return hu;
}

// ---------------- Kzero: zero the atomic-accumulation region ------------------
__global__ __launch_bounds__(256)
void kzero(float4* __restrict__ p) {
    p[blockIdx.x * 256 + threadIdx.x] = float4{0.f, 0.f, 0.f, 0.f};
}

// ---------------- Ksplit: presplit W1/W2 into hi/lo bf16 ----------------------
__global__ __launch_bounds__(256)
void ksplit(const float* __restrict__ w1, const float* __restrict__ w2,
            unsigned short* __restrict__ w1h, unsigned short* __restrict__ w1l,
            unsigned short* __restrict__ w2h, unsigned short* __restrict__ w2l) {
    int e = (blockIdx.x * 256 + threadIdx.x) * 4;
    const float* src; unsigned short *dh, *dl;
    if (e < 65536) { src = w1 + e; dh = w1h + e; dl = w1l + e; }
    else { int e2 = e - 65536; src = w2 + e2; dh = w2h + e2; dl = w2l + e2; }
    #pragma unroll
    for (int j = 0; j < 4; j++) splitstore(dh + j, dl + j, src[j]);
}

// ---------------- K0: w~ = W1[t]^T @ a  (f1 rows 0..3, f2 rows 4..7) ----------
__global__ __launch_bounds__(64)
void k0_wtilde(const float* __restrict__ w1,
               const float* __restrict__ a11,
               const float* __restrict__ a21,
               float* __restrict__ wt) {
    int wg = blockIdx.x;
    int t = wg & 3, which = wg >> 2;
    const float* a = which ? a21 : a11;
    int lane = threadIdx.x;
    float acc0 = 0.f, acc1 = 0.f, acc2 = 0.f, acc3 = 0.f;
    for (int d = 0; d < 64; d++) {
        float av = a[t * 64 + d];
        const float* wr = w1 + (t * 64 + d) * 256 + lane * 4;
        acc0 += av * wr[0]; acc1 += av * wr[1];
        acc2 += av * wr[2]; acc3 += av * wr[3];
    }
    float* o = wt + (which * 4 + t) * 256 + lane * 4;
    o[0] = acc0; o[1] = acc1; o[2] = acc2; o[3] = acc3;
}

// ---------------- Kpre: adjacency bitmask via ballot --------------------------
__global__ __launch_bounds__(256)
void kpre_bitmask(const int* __restrict__ adj, unsigned long long* __restrict__ bm) {
    int row = blockIdx.x;
    int wave = threadIdx.x >> 6, lane = threadIdx.x & 63;
    #pragma unroll
    for (int it = 0; it < 16; it++) {
        int jb = it * 256 + wave * 64;
        int v = adj[row * 4096 + jb + lane];
        unsigned long long mask = __ballot(v != 0);
        if (lane == 0) bm[row * 64 + (jb >> 6)] = mask;
    }
}

// ---------------- K1: H1T[c][i] = (x @ W1^T)[i][c], hi bf16 out ---------------
__global__ __launch_bounds__(256)
void k1_gemm(const float* __restrict__ x,
             const unsigned short* __restrict__ w1h,
             const unsigned short* __restrict__ w1l,
             unsigned short* __restrict__ h1t_hi) {
    int tid = threadIdx.x, wave = tid >> 6, lane = tid & 63;
    int q = lane >> 4, m = lane & 15;
    int i0 = blockIdx.x * 16;
    int c0 = wave * 64;
    f32x4 acc[4] = {};
    #pragma unroll
    for (int k0 = 0; k0 < 256; k0 += 32) {
        bf16x8 ah, al;
        split8(x + (i0 + m) * 256 + k0 + q * 8, ah, al);
        #pragma unroll
        for (int ct = 0; ct < 4; ct++) {
            bf16x8 bh = *(const bf16x8*)(w1h + (c0 + ct * 16 + m) * 256 + k0 + q * 8);
            bf16x8 bl = *(const bf16x8*)(w1l + (c0 + ct * 16 + m) * 256 + k0 + q * 8);
            acc[ct] = __builtin_amdgcn_mfma_f32_16x16x32_bf16(ah, bh, acc[ct], 0, 0, 0);
            acc[ct] = __builtin_amdgcn_mfma_f32_16x16x32_bf16(al, bh, acc[ct], 0, 0, 0);
            acc[ct] = __builtin_amdgcn_mfma_f32_16x16x32_bf16(ah, bl, acc[ct], 0, 0, 0);
        }
    }
    #pragma unroll
    for (int ct = 0; ct < 4; ct++)
        #pragma unroll
        for (int r = 0; r < 4; r++) {
            int c = c0 + ct * 16 + m, i = i0 + q * 4 + r;
            h1t_hi[c * 4096 + i] = f2bfh(acc[ct][r]);
        }
}

// ---------------- K1c: f1/f2 = x @ w~  ([8][4096] f32, exact) -----------------
__global__ __launch_bounds__(256)
void k1c_fvals(const float* __restrict__ x,
               const float* __restrict__ wt,
               float* __restrict__ fout) {
    int tid = threadIdx.x, wave = tid >> 6, lane = tid & 63;
    int i = blockIdx.x * 4 + wave;
    const float4 xv = *(const float4*)(x + i * 256 + lane * 4);
    #pragma unroll
    for (int a = 0; a < 8; a++) {
        const float4 wv = *(const float4*)(wt + a * 256 + lane * 4);
        float s = xv.x * wv.x + xv.y * wv.y + xv.z * wv.z + xv.w * wv.w;
        #pragma unroll
        for (int off = 32; off >= 1; off >>= 1) s += __shfl_xor(s, off);
        if (lane == 0) fout[a * 4096 + i] = s;
    }
}

// ---------------- attention (128-row tiles, j-split, atomic partials) ---------
// no-max-subtraction softmax (e bounded), P in hi/lo bf16 (A side), H hi-only
// (B side; lo term dropped -- alpha-weighted mean-zero residue, ~1e-4).
// grid (32 i-tiles of 128 rows, heads, 16 j-chunks of 256); 4 waves, each wave
// covers 32 rows via 2 A-frags sharing every BT fragment. Bitmask staged in LDS.
template<int NCT>
__global__ __launch_bounds__(256)
void attn_kernel(const unsigned char* __restrict__ bmb,
                 const float* __restrict__ f1_all,
                 const float* __restrict__ f2_all,
                 const unsigned short* __restrict__ BTh_all,
                 float* __restrict__ pacc,
                 float* __restrict__ zacc,
                 int pstride) {
    int tid = threadIdx.x, wave = tid >> 6, lane = tid & 63;
    int q = lane >> 4, m = lane & 15;
    int head = blockIdx.y;
    int i0 = blockIdx.x * 128;
    int jc = blockIdx.z;
    int jstart = jc * 256;

    // stage bitmask slice: 128 rows x 32 B  (rows i0.., j bits jstart..+255)
    __shared__ unsigned int ldsbm[128 * 8];
    {
        int row = tid >> 1, half = tid & 1;
        uint4 v = *(const uint4*)(bmb + (size_t)(i0 + row) * 512 + jc * 32 + half * 16);
        *(uint4*)&ldsbm[row * 8 + half * 4] = v;
    }
    __syncthreads();

    const float* f1 = f1_all + head * 4096;
    const float* f2 = f2_all + head * 4096;
    const unsigned short* BTh = BTh_all + head * NCT * 16 * 4096;
    int col0 = head * NCT * 16;

    int r0 = wave * 32;                       // wave's local row base
    float f1s0 = f1[i0 + r0 + m];
    float f1s1 = f1[i0 + r0 + 16 + m];

    f32x4 acc0[NCT] = {}, acc1[NCT] = {};
    float z0 = 0.f, z1 = 0.f;

    #pragma unroll 2
    for (int jl = 0; jl < 256; jl += 32) {
        unsigned int md0 = ldsbm[(r0 + m) * 8 + (jl >> 5)];
        unsigned int md1 = ldsbm[(r0 + 16 + m) * 8 + (jl >> 5)];
        const float4* f2p = (const float4*)(f2 + jstart + jl + q * 8);
        float4 fa = f2p[0], fb = f2p[1];
        float fv[8] = {fa.x, fa.y, fa.z, fa.w, fb.x, fb.y, fb.z, fb.w};
        float pv0[8], pv1[8];
        #pragma unroll
        for (int jj = 0; jj < 8; jj++) {
            int bit = q * 8 + jj;
            float s0 = f1s0 + fv[jj];
            float e0 = fmaxf(s0, 0.01f * s0);
            bool v0 = ((md0 >> bit) & 1u) && (s0 != 0.0f);
            float p0 = v0 ? __expf(e0) : 0.0f;
            z0 += p0; pv0[jj] = p0;
            float s1 = f1s1 + fv[jj];
            float e1 = fmaxf(s1, 0.01f * s1);
            bool v1 = ((md1 >> bit) & 1u) && (s1 != 0.0f);
            float p1 = v1 ? __expf(e1) : 0.0f;
            z1 += p1; pv1[jj] = p1;
        }
        bf16x8 ah0, al0, ah1, al1;
        split8(pv0, ah0, al0);
        split8(pv1, ah1, al1);
        #pragma unroll
        for (int ct = 0; ct < NCT; ct++) {
            bf16x8 bh = *(const bf16x8*)(BTh + (size_t)(ct * 16 + m) * 4096 + jstart + jl + q * 8);
            acc0[ct] = __builtin_amdgcn_mfma_f32_16x16x32_bf16(ah0, bh, acc0[ct], 0, 0, 0);
            acc0[ct] = __builtin_amdgcn_mfma_f32_16x16x32_bf16(al0, bh, acc0[ct], 0, 0, 0);
            acc1[ct] = __builtin_amdgcn_mfma_f32_16x16x32_bf16(ah1, bh, acc1[ct], 0, 0, 0);
            acc1[ct] = __builtin_amdgcn_mfma_f32_16x16x32_bf16(al1, bh, acc1[ct], 0, 0, 0);
        }
    }
    // reduce z over quads (q in lane bits 4-5)
    z0 += __shfl_xor(z0, 16); z0 += __shfl_xor(z0, 32);
    z1 += __shfl_xor(z1, 16); z1 += __shfl_xor(z1, 32);
    if (lane < 16) {
        atomicAdd(&zacc[head * 4096 + i0 + r0 + lane], z0);
        atomicAdd(&zacc[head * 4096 + i0 + r0 + 16 + lane], z1);
    }
    #pragma unroll
    for (int ct = 0; ct < NCT; ct++)
        #pragma unroll
        for (int r = 0; r < 4; r++) {
            int col = col0 + ct * 16 + m;
            atomicAdd(&pacc[(i0 + r0 + q * 4 + r) * pstride + col], acc0[ct][r]);
            atomicAdd(&pacc[(i0 + r0 + 16 + q * 4 + r) * pstride + col], acc1[ct][r]);
        }
}

// ---------------- Fin1: helu = elu(p1/z1), hi/lo bf16 -------------------------
__global__ __launch_bounds__(256)
void fin1(const float* __restrict__ pacc, const float* __restrict__ zacc,
          unsigned short* __restrict__ hh, unsigned short* __restrict__ hl) {
    int t = threadIdx.x;
    int row = blockIdx.x * 16 + (t >> 4);
    int c0 = (t & 15) * 16;
    int head = c0 >> 6;
    float rz = 1.0f / zacc[head * 4096 + row];
    #pragma unroll
    for (int c = c0; c < c0 + 16; c++) {
        float v = pacc[row * 256 + c] * rz;
        v = (v > 0.f) ? v : (__expf(v) - 1.0f);
        splitstore(&hh[row * 256 + c], &hl[row * 256 + c], v);
    }
}

// ---------------- Fin2: out = p2/z2 (f32) -------------------------------------
__global__ __launch_bounds__(256)
void fin2(const float* __restrict__ pacc, const float* __restrict__ zacc,
          float* __restrict__ out) {
    int idx = blockIdx.x * 256 + threadIdx.x;      // 65536
    out[idx] = pacc[idx] / zacc[idx >> 4];
}

// ---------------- K3: h2 = h_elu @ W2^T (hi/lo), f1_2/f2_2, h2T hi ------------
__global__ __launch_bounds__(256)
void k3_layer2(const unsigned short* __restrict__ helu_hi,
               const unsigned short* __restrict__ helu_lo,
               const unsigned short* __restrict__ w2h,
               const unsigned short* __restrict__ w2l,
               const float* __restrict__ a12,
               const float* __restrict__ a22,
               unsigned short* __restrict__ h2t_hi,
               float* __restrict__ fq) {
    int tid = threadIdx.x, wave = tid >> 6, lane = tid & 63;
    int q = lane >> 4, m = lane & 15;
    int i0 = (blockIdx.x * 4 + wave) * 16;
    f32x4 acc = {};
    #pragma unroll
    for (int k0 = 0; k0 < 256; k0 += 32) {
        bf16x8 ah = *(const bf16x8*)(helu_hi + (i0 + m) * 256 + k0 + q * 8);
        bf16x8 al = *(const bf16x8*)(helu_lo + (i0 + m) * 256 + k0 + q * 8);
        bf16x8 bh = *(const bf16x8*)(w2h + m * 256 + k0 + q * 8);
        bf16x8 bl = *(const bf16x8*)(w2l + m * 256 + k0 + q * 8);
        acc = __builtin_amdgcn_mfma_f32_16x16x32_bf16(ah, bh, acc, 0, 0, 0);
        acc = __builtin_amdgcn_mfma_f32_16x16x32_bf16(al, bh, acc, 0, 0, 0);
        acc = __builtin_amdgcn_mfma_f32_16x16x32_bf16(ah, bl, acc, 0, 0, 0);
    }
    float a1v = a12[m], a2v = a22[m];
    #pragma unroll
    for (int r = 0; r < 4; r++) {
        float v = acc[r];
        int i = i0 + q * 4 + r;
        h2t_hi[m * 4096 + i] = f2bfh(v);
        float s1 = v * a1v, s2 = v * a2v;
        #pragma unroll
        for (int off = 1; off < 16; off <<= 1) {
            s1 += __shfl_xor(s1, off);
            s2 += __shfl_xor(s2, off);
        }
        if (m == 0) { fq[i] = s1; fq[4096 + i] = s2; }
    }
}

extern "C" void kernel_launch(void* const* d_in, const int* in_sizes, int n_in,
                              void* d_out, int out_size, void* d_ws, size_t ws_size,
                              hipStream_t stream) {
    const float* x   = (const float*)d_in[0];
    const int*   adj = (const int*)d_in[1];
    const float* w1  = (const float*)d_in[2];
    const float* a11 = (const float*)d_in[3];
    const float* a21 = (const float*)d_in[4];
    const float* w2  = (const float*)d_in[5];
    const float* a12 = (const float*)d_in[6];
    const float* a22 = (const float*)d_in[7];
    float* out = (float*)d_out;

    uint8_t* w = (uint8_t*)d_ws;
    unsigned long long* bm  = (unsigned long long*)(w);                       // 2 MB
    unsigned short* h1t_hi  = (unsigned short*)(w + (2u  << 20));             // 2 MB
    unsigned short* helu_hi = (unsigned short*)(w + (6u  << 20));             // 2 MB
    unsigned short* helu_lo = (unsigned short*)(w + (8u  << 20));             // 2 MB
    unsigned short* h2t_hi  = (unsigned short*)(w + (10u << 20));             // 128 KB
    float*          wt      = (float*)(w + (10u << 20) + (256u << 10));       // 8 KB
    float*          fvals   = (float*)(w + (10u << 20) + (288u << 10));       // 128 KB
    float*          fq      = (float*)(w + (10u << 20) + (416u << 10));       // 32 KB
    unsigned short* w1h     = (unsigned short*)(w + (10u << 20) + (448u << 10)); // 128 KB
    unsigned short* w1l     = (unsigned short*)(w + (10u << 20) + (576u << 10)); // 128 KB
    unsigned short* w2h     = (unsigned short*)(w + (10u << 20) + (704u << 10)); // 8 KB
    unsigned short* w2l     = (unsigned short*)(w + (10u << 20) + (712u << 10)); // 8 KB
    float*          p1      = (float*)(w + (10u << 20) + (720u << 10));       // 4 MB
    float*          z1      = p1 + 4096 * 256;                                // 64 KB
    float*          p2      = z1 + 4 * 4096;                                  // 256 KB
    float*          z2      = p2 + 4096 * 16;                                 // 16 KB

    kzero<<<1108, 256, 0, stream>>>((float4*)p1);
    ksplit<<<68, 256, 0, stream>>>(w1, w2, w1h, w1l, w2h, w2l);
    k0_wtilde<<<8, 64, 0, stream>>>(w1, a11, a21, wt);
    kpre_bitmask<<<4096, 256, 0, stream>>>(adj, bm);
    k1_gemm<<<256, 256, 0, stream>>>(x, w1h, w1l, h1t_hi);
    k1c_fvals<<<1024, 256, 0, stream>>>(x, wt, fvals);
    attn_kernel<4><<<dim3(32, 4, 16), 256, 0, stream>>>(
        (const unsigned char*)bm, fvals, fvals + 4 * 4096, h1t_hi, p1, z1, 256);
    fin1<<<256, 256, 0, stream>>>(p1, z1, helu_hi, helu_lo);
    k3_layer2<<<64, 256, 0, stream>>>(helu_hi, helu_lo, w2h, w2l, a12, a22,
                                      h2t_hi, fq);
    attn_kernel<1><<<dim3(32, 1, 16), 256, 0, stream>>>(
        (const unsigned char*)bm, fq, fq + 4096, h2t_hi, p2, z2, 16);
    fin2<<<256, 256, 0, stream>>>(p2, z2, out);
}

// Round 6
// 233.233 us; speedup vs baseline: 1.5313x; 1.0420x over previous
//
#include <hip/hip_runtime.h>
#include <cstdint>

typedef __bf16 bf16x8 __attribute__((ext_vector_type(8)));
typedef float  f32x4  __attribute__((ext_vector_type(4)));

// split 8 f32 into hi/lo bf16 fragments (hi+lo ~ 16-bit mantissa)
__device__ __forceinline__ void split8(const float* v, bf16x8& hi, bf16x8& lo) {
    union { bf16x8 v; __bf16 e[8]; } h, l;
    #pragma unroll
    for (int j = 0; j < 8; j++) {
        __bf16 hb = (__bf16)v[j];
        float  r  = v[j] - (float)hb;
        h.e[j] = hb; l.e[j] = (__bf16)r;
    }
    hi = h.v; lo = l.v;
}
__device__ __forceinline__ void splitstore(unsigned short* ph, unsigned short* pl, float v) {
    __bf16 hb = (__bf16)v;
    float  r  = v - (float)hb;
    __bf16 lb = (__bf16)r;
    unsigned short hu, lu;
    __builtin_memcpy(&hu, &hb, 2); __builtin_memcpy(&lu, &lb, 2);
    *ph = hu; *pl = lu;
}
__device__ __forceinline__ unsigned short f2bfh(float v) {
    __bf16 hb = (__bf16)v; unsigned short hu;
    __builtin_memcpy(&hu, &hb, 2); return hu;
}

// ---------------- Kzero: zero the atomic-accumulation region (fallback) -------
__global__ __launch_bounds__(256)
void kzero(float4* __restrict__ p) {
    p[blockIdx.x * 256 + threadIdx.x] = float4{0.f, 0.f, 0.f, 0.f};
}

// ---------------- Ksplit: presplit W1/W2 into hi/lo bf16 ----------------------
__global__ __launch_bounds__(256)
void ksplit(const float* __restrict__ w1, const float* __restrict__ w2,
            unsigned short* __restrict__ w1h, unsigned short* __restrict__ w1l,
            unsigned short* __restrict__ w2h, unsigned short* __restrict__ w2l) {
    int e = (blockIdx.x * 256 + threadIdx.x) * 4;
    const float* src; unsigned short *dh, *dl;
    if (e < 65536) { src = w1 + e; dh = w1h + e; dl = w1l + e; }
    else { int e2 = e - 65536; src = w2 + e2; dh = w2h + e2; dl = w2l + e2; }
    #pragma unroll
    for (int j = 0; j < 4; j++) splitstore(dh + j, dl + j, src[j]);
}

// ---------------- K0: w~ = W1[t]^T @ a  (f1 rows 0..3, f2 rows 4..7) ----------
__global__ __launch_bounds__(64)
void k0_wtilde(const float* __restrict__ w1,
               const float* __restrict__ a11,
               const float* __restrict__ a21,
               float* __restrict__ wt) {
    int wg = blockIdx.x;
    int t = wg & 3, which = wg >> 2;
    const float* a = which ? a21 : a11;
    int lane = threadIdx.x;
    float acc0 = 0.f, acc1 = 0.f, acc2 = 0.f, acc3 = 0.f;
    for (int d = 0; d < 64; d++) {
        float av = a[t * 64 + d];
        const float* wr = w1 + (t * 64 + d) * 256 + lane * 4;
        acc0 += av * wr[0]; acc1 += av * wr[1];
        acc2 += av * wr[2]; acc3 += av * wr[3];
    }
    float* o = wt + (which * 4 + t) * 256 + lane * 4;
    o[0] = acc0; o[1] = acc1; o[2] = acc2; o[3] = acc3;
}

// ---------------- Kpre: adjacency bitmask via ballot --------------------------
__global__ __launch_bounds__(256)
void kpre_bitmask(const int* __restrict__ adj, unsigned long long* __restrict__ bm) {
    int row = blockIdx.x;
    int wave = threadIdx.x >> 6, lane = threadIdx.x & 63;
    #pragma unroll
    for (int it = 0; it < 16; it++) {
        int jb = it * 256 + wave * 64;
        int v = adj[row * 4096 + jb + lane];
        unsigned long long mask = __ballot(v != 0);
        if (lane == 0) bm[row * 64 + (jb >> 6)] = mask;
    }
}

// ---------------- K1: H1T[c][i] = (x @ W1^T)[i][c], hi bf16 out ---------------
__global__ __launch_bounds__(256)
void k1_gemm(const float* __restrict__ x,
             const unsigned short* __restrict__ w1h,
             const unsigned short* __restrict__ w1l,
             unsigned short* __restrict__ h1t_hi) {
    int tid = threadIdx.x, wave = tid >> 6, lane = tid & 63;
    int q = lane >> 4, m = lane & 15;
    int i0 = blockIdx.x * 16;
    int c0 = wave * 64;
    f32x4 acc[4] = {};
    #pragma unroll
    for (int k0 = 0; k0 < 256; k0 += 32) {
        bf16x8 ah, al;
        split8(x + (i0 + m) * 256 + k0 + q * 8, ah, al);
        #pragma unroll
        for (int ct = 0; ct < 4; ct++) {
            bf16x8 bh = *(const bf16x8*)(w1h + (c0 + ct * 16 + m) * 256 + k0 + q * 8);
            bf16x8 bl = *(const bf16x8*)(w1l + (c0 + ct * 16 + m) * 256 + k0 + q * 8);
            acc[ct] = __builtin_amdgcn_mfma_f32_16x16x32_bf16(ah, bh, acc[ct], 0, 0, 0);
            acc[ct] = __builtin_amdgcn_mfma_f32_16x16x32_bf16(al, bh, acc[ct], 0, 0, 0);
            acc[ct] = __builtin_amdgcn_mfma_f32_16x16x32_bf16(ah, bl, acc[ct], 0, 0, 0);
        }
    }
    #pragma unroll
    for (int ct = 0; ct < 4; ct++)
        #pragma unroll
        for (int r = 0; r < 4; r++) {
            int c = c0 + ct * 16 + m, i = i0 + q * 4 + r;
            h1t_hi[c * 4096 + i] = f2bfh(acc[ct][r]);
        }
}

// ---------------- K1c: f1/f2 = x @ w~  ([8][4096] f32, exact) -----------------
__global__ __launch_bounds__(256)
void k1c_fvals(const float* __restrict__ x,
               const float* __restrict__ wt,
               float* __restrict__ fout) {
    int tid = threadIdx.x, wave = tid >> 6, lane = tid & 63;
    int i = blockIdx.x * 4 + wave;
    const float4 xv = *(const float4*)(x + i * 256 + lane * 4);
    #pragma unroll
    for (int a = 0; a < 8; a++) {
        const float4 wv = *(const float4*)(wt + a * 256 + lane * 4);
        float s = xv.x * wv.x + xv.y * wv.y + xv.z * wv.z + xv.w * wv.w;
        #pragma unroll
        for (int off = 32; off >= 1; off >>= 1) s += __shfl_xor(s, off);
        if (lane == 0) fout[a * 4096 + i] = s;
    }
}

// ---------------- attention (128-row tiles, j-split, DISJOINT partials) -------
// no-max-subtraction softmax (e bounded), P hi/lo bf16 (A side), H hi-only (B).
// grid (32 i-tiles of 128 rows, heads, NJ j-chunks of JLEN); 4 waves x 32 rows.
// ATOM=false: each j-chunk writes its own partial slice (plain stores, no
// cross-XCD atomic ping-pong). ATOM=true: legacy atomicAdd fallback (small ws).
template<int NCT, int JLEN, bool ATOM>
__global__ __launch_bounds__(256)
void attn_kernel(const unsigned char* __restrict__ bmb,
                 const float* __restrict__ f1_all,
                 const float* __restrict__ f2_all,
                 const unsigned short* __restrict__ BTh_all,
                 float* __restrict__ pacc,
                 float* __restrict__ zacc,
                 int pstride) {
    constexpr int S  = JLEN / 32;   // mask uints per row
    constexpr int PR = S / 4;       // mask uint4 per row
    int tid = threadIdx.x, wave = tid >> 6, lane = tid & 63;
    int q = lane >> 4, m = lane & 15;
    int head = blockIdx.y;
    int i0 = blockIdx.x * 128;
    int jstart = blockIdx.z * JLEN;

    if (!ATOM) {
        pacc += (size_t)blockIdx.z * (size_t)(4096 * pstride);
        zacc += (size_t)blockIdx.z * (size_t)((NCT == 4 ? 4 : 1) * 4096);
    }

    // stage bitmask slice: 128 rows x JLEN/8 bytes
    __shared__ unsigned int ldsbm[128 * S];
    for (int c = tid; c < 32 * S; c += 256) {
        int row = c / PR, part = c % PR;
        uint4 v = *(const uint4*)(bmb + (size_t)(i0 + row) * 512 + (jstart >> 3) + part * 16);
        *(uint4*)&ldsbm[row * S + part * 4] = v;
    }
    __syncthreads();

    const float* f1 = f1_all + head * 4096;
    const float* f2 = f2_all + head * 4096;
    const unsigned short* BTh = BTh_all + (size_t)head * NCT * 16 * 4096;
    int col0 = head * NCT * 16;

    int r0 = wave * 32;
    float f1s0 = f1[i0 + r0 + m];
    float f1s1 = f1[i0 + r0 + 16 + m];

    f32x4 acc0[NCT] = {}, acc1[NCT] = {};
    float z0 = 0.f, z1 = 0.f;

    #pragma unroll 2
    for (int jl = 0; jl < JLEN; jl += 32) {
        unsigned int md0 = ldsbm[(r0 + m) * S + (jl >> 5)];
        unsigned int md1 = ldsbm[(r0 + 16 + m) * S + (jl >> 5)];
        const float4* f2p = (const float4*)(f2 + jstart + jl + q * 8);
        float4 fa = f2p[0], fb = f2p[1];
        float fv[8] = {fa.x, fa.y, fa.z, fa.w, fb.x, fb.y, fb.z, fb.w};
        float pv0[8], pv1[8];
        #pragma unroll
        for (int jj = 0; jj < 8; jj++) {
            int bit = q * 8 + jj;
            float s0 = f1s0 + fv[jj];
            float e0 = fmaxf(s0, 0.01f * s0);
            bool v0 = ((md0 >> bit) & 1u) && (s0 != 0.0f);
            float p0 = v0 ? __expf(e0) : 0.0f;
            z0 += p0; pv0[jj] = p0;
            float s1 = f1s1 + fv[jj];
            float e1 = fmaxf(s1, 0.01f * s1);
            bool v1 = ((md1 >> bit) & 1u) && (s1 != 0.0f);
            float p1 = v1 ? __expf(e1) : 0.0f;
            z1 += p1; pv1[jj] = p1;
        }
        bf16x8 ah0, al0, ah1, al1;
        split8(pv0, ah0, al0);
        split8(pv1, ah1, al1);
        #pragma unroll
        for (int ct = 0; ct < NCT; ct++) {
            bf16x8 bh = *(const bf16x8*)(BTh + (size_t)(ct * 16 + m) * 4096 + jstart + jl + q * 8);
            acc0[ct] = __builtin_amdgcn_mfma_f32_16x16x32_bf16(ah0, bh, acc0[ct], 0, 0, 0);
            acc0[ct] = __builtin_amdgcn_mfma_f32_16x16x32_bf16(al0, bh, acc0[ct], 0, 0, 0);
            acc1[ct] = __builtin_amdgcn_mfma_f32_16x16x32_bf16(ah1, bh, acc1[ct], 0, 0, 0);
            acc1[ct] = __builtin_amdgcn_mfma_f32_16x16x32_bf16(al1, bh, acc1[ct], 0, 0, 0);
        }
    }
    z0 += __shfl_xor(z0, 16); z0 += __shfl_xor(z0, 32);
    z1 += __shfl_xor(z1, 16); z1 += __shfl_xor(z1, 32);
    if (lane < 16) {
        if (ATOM) {
            atomicAdd(&zacc[head * 4096 + i0 + r0 + lane], z0);
            atomicAdd(&zacc[head * 4096 + i0 + r0 + 16 + lane], z1);
        } else {
            zacc[head * 4096 + i0 + r0 + lane] = z0;
            zacc[head * 4096 + i0 + r0 + 16 + lane] = z1;
        }
    }
    #pragma unroll
    for (int ct = 0; ct < NCT; ct++)
        #pragma unroll
        for (int r = 0; r < 4; r++) {
            int col = col0 + ct * 16 + m;
            if (ATOM) {
                atomicAdd(&pacc[(i0 + r0 + q * 4 + r) * pstride + col], acc0[ct][r]);
                atomicAdd(&pacc[(i0 + r0 + 16 + q * 4 + r) * pstride + col], acc1[ct][r]);
            } else {
                pacc[(i0 + r0 + q * 4 + r) * pstride + col] = acc0[ct][r];
                pacc[(i0 + r0 + 16 + q * 4 + r) * pstride + col] = acc1[ct][r];
            }
        }
}

// ---------------- Fin1: helu = elu(sum(p1)/sum(z1)), hi/lo bf16 ---------------
__global__ __launch_bounds__(256)
void fin1(const float* __restrict__ pp, const float* __restrict__ zp, int nj,
          unsigned short* __restrict__ hh, unsigned short* __restrict__ hl) {
    int row = blockIdx.x, col = threadIdx.x;
    float s = 0.f;
    for (int jc = 0; jc < nj; jc++) s += pp[(size_t)jc * (4096 * 256) + row * 256 + col];
    int head = col >> 6;
    float zz = 0.f;
    for (int jc = 0; jc < nj; jc++) zz += zp[jc * (4 * 4096) + head * 4096 + row];
    float v = s / zz;
    v = (v > 0.f) ? v : (__expf(v) - 1.0f);
    splitstore(&hh[row * 256 + col], &hl[row * 256 + col], v);
}

// ---------------- Fin2: out = sum(p2)/sum(z2) (f32) ---------------------------
__global__ __launch_bounds__(256)
void fin2(const float* __restrict__ pp, const float* __restrict__ zp, int nj,
          float* __restrict__ out) {
    int idx = blockIdx.x * 256 + threadIdx.x;      // 65536
    float s = 0.f;
    for (int jc = 0; jc < nj; jc++) s += pp[jc * 65536 + idx];
    float zz = 0.f;
    for (int jc = 0; jc < nj; jc++) zz += zp[jc * 4096 + (idx >> 4)];
    out[idx] = s / zz;
}

// ---------------- K3: h2 = h_elu @ W2^T (hi/lo), f1_2/f2_2, h2T hi ------------
__global__ __launch_bounds__(256)
void k3_layer2(const unsigned short* __restrict__ helu_hi,
               const unsigned short* __restrict__ helu_lo,
               const unsigned short* __restrict__ w2h,
               const unsigned short* __restrict__ w2l,
               const float* __restrict__ a12,
               const float* __restrict__ a22,
               unsigned short* __restrict__ h2t_hi,
               float* __restrict__ fq) {
    int tid = threadIdx.x, wave = tid >> 6, lane = tid & 63;
    int q = lane >> 4, m = lane & 15;
    int i0 = (blockIdx.x * 4 + wave) * 16;
    f32x4 acc = {};
    #pragma unroll
    for (int k0 = 0; k0 < 256; k0 += 32) {
        bf16x8 ah = *(const bf16x8*)(helu_hi + (i0 + m) * 256 + k0 + q * 8);
        bf16x8 al = *(const bf16x8*)(helu_lo + (i0 + m) * 256 + k0 + q * 8);
        bf16x8 bh = *(const bf16x8*)(w2h + m * 256 + k0 + q * 8);
        bf16x8 bl = *(const bf16x8*)(w2l + m * 256 + k0 + q * 8);
        acc = __builtin_amdgcn_mfma_f32_16x16x32_bf16(ah, bh, acc, 0, 0, 0);
        acc = __builtin_amdgcn_mfma_f32_16x16x32_bf16(al, bh, acc, 0, 0, 0);
        acc = __builtin_amdgcn_mfma_f32_16x16x32_bf16(ah, bl, acc, 0, 0, 0);
    }
    float a1v = a12[m], a2v = a22[m];
    #pragma unroll
    for (int r = 0; r < 4; r++) {
        float v = acc[r];
        int i = i0 + q * 4 + r;
        h2t_hi[m * 4096 + i] = f2bfh(v);
        float s1 = v * a1v, s2 = v * a2v;
        #pragma unroll
        for (int off = 1; off < 16; off <<= 1) {
            s1 += __shfl_xor(s1, off);
            s2 += __shfl_xor(s2, off);
        }
        if (m == 0) { fq[i] = s1; fq[4096 + i] = s2; }
    }
}

extern "C" void kernel_launch(void* const* d_in, const int* in_sizes, int n_in,
                              void* d_out, int out_size, void* d_ws, size_t ws_size,
                              hipStream_t stream) {
    const float* x   = (const float*)d_in[0];
    const int*   adj = (const int*)d_in[1];
    const float* w1  = (const float*)d_in[2];
    const float* a11 = (const float*)d_in[3];
    const float* a21 = (const float*)d_in[4];
    const float* w2  = (const float*)d_in[5];
    const float* a12 = (const float*)d_in[6];
    const float* a22 = (const float*)d_in[7];
    float* out = (float*)d_out;

    uint8_t* w = (uint8_t*)d_ws;
    unsigned long long* bm  = (unsigned long long*)(w);                       // 2 MB
    unsigned short* h1t_hi  = (unsigned short*)(w + (2u << 20));              // 2 MB
    unsigned short* helu_hi = (unsigned short*)(w + (4u << 20));              // 2 MB
    unsigned short* helu_lo = (unsigned short*)(w + (6u << 20));              // 2 MB
    unsigned short* h2t_hi  = (unsigned short*)(w + (8u << 20));              // 128 KB
    float*          wt      = (float*)(w + (8u << 20) + (128u << 10));        // 8 KB
    float*          fvals   = (float*)(w + (8u << 20) + (136u << 10));        // 128 KB
    float*          fq      = (float*)(w + (8u << 20) + (264u << 10));        // 32 KB
    unsigned short* w1h     = (unsigned short*)(w + (8u << 20) + (296u << 10)); // 128 KB
    unsigned short* w1l     = (unsigned short*)(w + (8u << 20) + (424u << 10)); // 128 KB
    unsigned short* w2h     = (unsigned short*)(w + (8u << 20) + (552u << 10)); // 8 KB
    unsigned short* w2l     = (unsigned short*)(w + (8u << 20) + (560u << 10)); // 8 KB

    bool big = ws_size >= ((size_t)51 << 20);
    float* p1 = (float*)(w + (9u << 20));
    float *z1, *p2, *z2;
    if (big) {
        z1 = p1 + (size_t)8 * 4096 * 256;       // p1: 8 x 4 MB = 32 MB
        p2 = z1 + 8 * 4 * 4096;                 // z1: 8 x 64 KB
        z2 = p2 + (size_t)32 * 4096 * 16;       // p2: 32 x 256 KB = 8 MB
    } else {
        z1 = p1 + 4096 * 256;                   // p1: 4 MB
        p2 = z1 + 4 * 4096;                     // z1: 64 KB
        z2 = p2 + 4096 * 16;                    // p2: 256 KB, z2: 16 KB
    }

    if (!big) kzero<<<1108, 256, 0, stream>>>((float4*)p1);
    ksplit<<<68, 256, 0, stream>>>(w1, w2, w1h, w1l, w2h, w2l);
    k0_wtilde<<<8, 64, 0, stream>>>(w1, a11, a21, wt);
    kpre_bitmask<<<4096, 256, 0, stream>>>(adj, bm);
    k1_gemm<<<256, 256, 0, stream>>>(x, w1h, w1l, h1t_hi);
    k1c_fvals<<<1024, 256, 0, stream>>>(x, wt, fvals);
    if (big)
        attn_kernel<4, 512, false><<<dim3(32, 4, 8), 256, 0, stream>>>(
            (const unsigned char*)bm, fvals, fvals + 4 * 4096, h1t_hi, p1, z1, 256);
    else
        attn_kernel<4, 512, true><<<dim3(32, 4, 8), 256, 0, stream>>>(
            (const unsigned char*)bm, fvals, fvals + 4 * 4096, h1t_hi, p1, z1, 256);
    fin1<<<4096, 256, 0, stream>>>(p1, z1, big ? 8 : 1, helu_hi, helu_lo);
    k3_layer2<<<64, 256, 0, stream>>>(helu_hi, helu_lo, w2h, w2l, a12, a22,
                                      h2t_hi, fq);
    if (big)
        attn_kernel<1, 128, false><<<dim3(32, 1, 32), 256, 0, stream>>>(
            (const unsigned char*)bm, fq, fq + 4096, h2t_hi, p2, z2, 16);
    else
        attn_kernel<1, 128, true><<<dim3(32, 1, 32), 256, 0, stream>>>(
            (const unsigned char*)bm, fq, fq + 4096, h2t_hi, p2, z2, 16);
    fin2<<<256, 256, 0, stream>>>(p2, z2, big ? 32 : 1, out);
}